// Round 7
// baseline (132.959 us; speedup 1.0000x reference)
//
#include <hip/hip_runtime.h>
#include <math.h>

#define N 4096
#define P 128
#define H 4
#define E 32
#define NSEG 32
#define TPB 256

// proj: 64-row tiles x 3 matrices = 192 tasks (+1 sort block = 193 blocks)
#define PROJ_TASKS 192

// attention: single-wave blocks, one query per lane
#define QW 3             // query-wave splits per (seg, head) -> grid z
#define KCH 64           // keys per LDS chunk
#define LROW 36          // padded LDS row stride in floats (breaks pow2 banks)
#define G 8              // key group size (chain-breaking batch)
#define NEGF -3.0e38f

// ---------------------------------------------------------------------------
// Counting sort (single block, LDS atomics).
// ---------------------------------------------------------------------------
__device__ __forceinline__ void sort_phase(const int* __restrict__ pos,
                                           int* __restrict__ seg_rows,
                                           int* __restrict__ seg_off,
                                           int* sm, int t) {
    int* cnt = sm;              // NSEG
    int* cur = sm + NSEG;       // NSEG
    int* off = sm + 2 * NSEG;   // NSEG+1
    if (t < NSEG) cnt[t] = 0;
    __syncthreads();
    for (int i = t; i < N; i += TPB) atomicAdd(&cnt[pos[i]], 1);
    __syncthreads();
    if (t == 0) {
        int s = 0;
        for (int k = 0; k < NSEG; ++k) { off[k] = s; s += cnt[k]; }
        off[NSEG] = s;
    }
    __syncthreads();
    if (t <= NSEG) seg_off[t] = off[t];
    if (t < NSEG) cur[t] = off[t];
    __syncthreads();
    for (int i = t; i < N; i += TPB) {
        int r = atomicAdd(&cur[pos[i]], 1);
        seg_rows[r] = i;
    }
}

// ---------------------------------------------------------------------------
// One 64-row QKV projection tile. task in [0,192): mat=task>>6, tile=task&63.
// sm: Xl [64][128] (32KB) + Wl [32][128] (16KB) = 48KB.
// ---------------------------------------------------------------------------
__device__ __forceinline__ void proj_phase(int task,
                                           const float* __restrict__ x,
                                           const float* __restrict__ Wq, const float* __restrict__ bq,
                                           const float* __restrict__ Wk, const float* __restrict__ bk,
                                           const float* __restrict__ Wv, const float* __restrict__ bv,
                                           float* __restrict__ Q, float* __restrict__ Ko, float* __restrict__ Vo,
                                           float* sm, int t) {
    float* Xl = sm;           // [64][128]
    float* Wl = sm + 8192;    // [32][128]

    const int mat = task >> 6;
    const int r0  = (task & 63) * 64;
    const float* W = (mat == 0) ? Wq : (mat == 1) ? Wk : Wv;
    const float* b = (mat == 0) ? bq : (mat == 1) ? bk : bv;
    float* y       = (mat == 0) ? Q  : (mat == 1) ? Ko : Vo;

    for (int i = t * 4; i < 64 * 128; i += TPB * 4) {
        *(float4*)(Xl + i) = *(const float4*)(x + (size_t)r0 * 128 + i);
    }

    const int tc = t & 31;   // cols 4*tc..4*tc+3
    const int tr = t >> 5;   // rows 8*tr..8*tr+7

    float4 bb = *(const float4*)(b + tc * 4);
    float4 acc[8];
#pragma unroll
    for (int r = 0; r < 8; ++r) acc[r] = bb;

    for (int kc = 0; kc < 128; kc += 32) {
        __syncthreads();
        for (int i = t * 4; i < 32 * 128; i += TPB * 4) {
            *(float4*)(Wl + i) = *(const float4*)(W + (size_t)kc * 128 + i);
        }
        __syncthreads();
#pragma unroll
        for (int k0 = 0; k0 < 32; k0 += 4) {
            float4 w0 = *(float4*)&Wl[(k0 + 0) * 128 + tc * 4];
            float4 w1 = *(float4*)&Wl[(k0 + 1) * 128 + tc * 4];
            float4 w2 = *(float4*)&Wl[(k0 + 2) * 128 + tc * 4];
            float4 w3 = *(float4*)&Wl[(k0 + 3) * 128 + tc * 4];
#pragma unroll
            for (int r = 0; r < 8; ++r) {
                float4 xv = *(float4*)&Xl[(tr * 8 + r) * 128 + kc + k0];
                acc[r].x = fmaf(xv.x, w0.x, acc[r].x);
                acc[r].y = fmaf(xv.x, w0.y, acc[r].y);
                acc[r].z = fmaf(xv.x, w0.z, acc[r].z);
                acc[r].w = fmaf(xv.x, w0.w, acc[r].w);
                acc[r].x = fmaf(xv.y, w1.x, acc[r].x);
                acc[r].y = fmaf(xv.y, w1.y, acc[r].y);
                acc[r].z = fmaf(xv.y, w1.z, acc[r].z);
                acc[r].w = fmaf(xv.y, w1.w, acc[r].w);
                acc[r].x = fmaf(xv.z, w2.x, acc[r].x);
                acc[r].y = fmaf(xv.z, w2.y, acc[r].y);
                acc[r].z = fmaf(xv.z, w2.z, acc[r].z);
                acc[r].w = fmaf(xv.z, w2.w, acc[r].w);
                acc[r].x = fmaf(xv.w, w3.x, acc[r].x);
                acc[r].y = fmaf(xv.w, w3.y, acc[r].y);
                acc[r].z = fmaf(xv.w, w3.z, acc[r].z);
                acc[r].w = fmaf(xv.w, w3.w, acc[r].w);
            }
        }
    }

#pragma unroll
    for (int r = 0; r < 8; ++r) {
        *(float4*)(y + (size_t)(r0 + tr * 8 + r) * 128 + tc * 4) = acc[r];
    }
}

// ---------------------------------------------------------------------------
// Dispatch 1: block 0 sorts; blocks 1..192 each do one 64-row proj tile.
// ---------------------------------------------------------------------------
__global__ __launch_bounds__(TPB) void sort_proj_kernel(
        const float* __restrict__ inp, const int* __restrict__ pos,
        const float* __restrict__ Wq, const float* __restrict__ bq,
        const float* __restrict__ Wk, const float* __restrict__ bk,
        const float* __restrict__ Wv, const float* __restrict__ bv,
        float* __restrict__ Q, float* __restrict__ Kb, float* __restrict__ Vb,
        int* __restrict__ seg_rows, int* __restrict__ seg_off) {
    __shared__ __align__(16) float sm[12288];   // 48 KB
    const int b = blockIdx.x;
    const int t = threadIdx.x;
    if (b == 0) {
        sort_phase(pos, seg_rows, seg_off, (int*)sm, t);
    } else {
        proj_phase(b - 1, inp, Wq, bq, Wk, bk, Wv, bv, Q, Kb, Vb, sm, t);
    }
}

// ---------------------------------------------------------------------------
// Dispatch 2: attention. ONE WAVE per block, ONE QUERY PER LANE.
// Grid (NSEG, H, QW), block 64. Lane owns q[32]/acc[32] in registers; K/V
// rows are broadcast-read from LDS (wave-uniform addresses, conflict-free).
// No shfl, no multi-wave barriers. Group-batched online softmax (G=8).
// ---------------------------------------------------------------------------
__global__ __launch_bounds__(64) void attn_kernel(const float* __restrict__ Q,
                                                  const float* __restrict__ K,
                                                  const float* __restrict__ V,
                                                  const int* __restrict__ seg_rows,
                                                  const int* __restrict__ seg_off,
                                                  float* __restrict__ out) {
    __shared__ __align__(16) float Ks[KCH * LROW];   // 9 KB
    __shared__ __align__(16) float Vs[KCH * LROW];   // 9 KB

    const int s    = blockIdx.x;
    const int h    = blockIdx.y;
    const int z    = blockIdx.z;
    const int beg  = seg_off[s];
    const int len  = seg_off[s + 1] - beg;
    const int lane = threadIdx.x;
    if (z * 64 >= len) return;                 // dead query-wave: exit now
    const float scale = 0.17677669529663687f;  // 1/sqrt(32)

    for (int qb = z * 64; qb < len; qb += QW * 64) {
        const int  qi     = qb + lane;
        const bool active = (qi < len);
        const int  qrow   = seg_rows[beg + (active ? qi : 0)];

        float q[E];
        {
            const float* qp = Q + (size_t)qrow * P + h * E;
#pragma unroll
            for (int e = 0; e < E; e += 4) {
                float4 v4 = *(const float4*)(qp + e);
                q[e] = v4.x; q[e + 1] = v4.y; q[e + 2] = v4.z; q[e + 3] = v4.w;
            }
        }

        float m = NEGF, l = 0.f;
        float acc[E];
#pragma unroll
        for (int e = 0; e < E; ++e) acc[e] = 0.f;

        for (int cb = 0; cb < len; cb += KCH) {
            const int cl = min(KCH, len - cb);
            // stage K/V chunk; lanes cover consecutive e -> coalesced global,
            // conflict-free LDS (stride LROW=36 breaks pow2 pattern)
            for (int idx = lane; idx < cl * E; idx += 64) {
                const int r = idx >> 5, e = idx & 31;
                const int krow = seg_rows[beg + cb + r];
                Ks[r * LROW + e] = K[(size_t)krow * P + h * E + e];
                Vs[r * LROW + e] = V[(size_t)krow * P + h * E + e];
            }
            __syncthreads();   // single wave: compiles to a cheap waitcnt+barrier

            for (int g = 0; g < cl; g += G) {
                // phase 1: G independent dots (broadcast LDS reads)
                float sc[G];
                int   ro[G];
#pragma unroll
                for (int i = 0; i < G; ++i) {
                    const int r = g + i;
                    ro[i] = (r < cl ? r : cl - 1) * LROW;
                    const float* kr = Ks + ro[i];
                    float d0 = 0.f, d1 = 0.f, d2 = 0.f, d3 = 0.f;
#pragma unroll
                    for (int e = 0; e < E; e += 4) {
                        float4 kv = *(const float4*)(kr + e);
                        d0 = fmaf(q[e],     kv.x, d0);
                        d1 = fmaf(q[e + 1], kv.y, d1);
                        d2 = fmaf(q[e + 2], kv.z, d2);
                        d3 = fmaf(q[e + 3], kv.w, d3);
                    }
                    const float d = (d0 + d1) + (d2 + d3);
                    sc[i] = (r < cl) ? d * scale : NEGF;
                }
                // phase 2: one group max + correction
                const float g0 = fmaxf(fmaxf(sc[0], sc[1]), fmaxf(sc[2], sc[3]));
                const float g1 = fmaxf(fmaxf(sc[4], sc[5]), fmaxf(sc[6], sc[7]));
                const float mn   = fmaxf(m, fmaxf(g0, g1));
                const float corr = __expf(m - mn);
                m = mn;
                // phase 3: G independent exps
                float p[G];
#pragma unroll
                for (int i = 0; i < G; ++i) p[i] = __expf(sc[i] - mn);
                const float sp = ((p[0] + p[1]) + (p[2] + p[3]))
                               + ((p[4] + p[5]) + (p[6] + p[7]));
                l = fmaf(l, corr, sp);
                // phase 4: rescale once, then G-deep independent FMA trees
#pragma unroll
                for (int e = 0; e < E; ++e) acc[e] *= corr;
#pragma unroll
                for (int i = 0; i < G; ++i) {
                    const float* vr = Vs + ro[i];
                    const float pi = p[i];
#pragma unroll
                    for (int e = 0; e < E; e += 4) {
                        float4 vv = *(const float4*)(vr + e);
                        acc[e]     = fmaf(pi, vv.x, acc[e]);
                        acc[e + 1] = fmaf(pi, vv.y, acc[e + 1]);
                        acc[e + 2] = fmaf(pi, vv.z, acc[e + 2]);
                        acc[e + 3] = fmaf(pi, vv.w, acc[e + 3]);
                    }
                }
            }
            __syncthreads();   // keep staging of next chunk behind these reads
        }

        if (active) {
            const float inv = 1.0f / l;
            float* op = out + (size_t)qrow * P + h * E;
#pragma unroll
            for (int e = 0; e < E; e += 4) {
                *(float4*)(op + e) = make_float4(acc[e] * inv, acc[e + 1] * inv,
                                                 acc[e + 2] * inv, acc[e + 3] * inv);
            }
        }
    }
}

// ---------------------------------------------------------------------------
extern "C" void kernel_launch(void* const* d_in, const int* in_sizes, int n_in,
                              void* d_out, int out_size, void* d_ws, size_t ws_size,
                              hipStream_t stream) {
    const float* inp = (const float*)d_in[0];
    const int*   pos = (const int*)d_in[1];
    const float* Wq  = (const float*)d_in[2];
    const float* bq  = (const float*)d_in[3];
    const float* Wk  = (const float*)d_in[4];
    const float* bk  = (const float*)d_in[5];
    const float* Wv  = (const float*)d_in[6];
    const float* bv  = (const float*)d_in[7];
    float* out = (float*)d_out;

    float* Q  = (float*)d_ws;
    float* Kb = Q + (size_t)N * P;
    float* Vb = Kb + (size_t)N * P;
    int* seg_rows = (int*)(Vb + (size_t)N * P);
    int* seg_off  = seg_rows + N;          // NSEG+1

    sort_proj_kernel<<<1 + PROJ_TASKS, TPB, 0, stream>>>(
        inp, pos, Wq, bq, Wk, bk, Wv, bv, Q, Kb, Vb, seg_rows, seg_off);

    attn_kernel<<<dim3(NSEG, H, QW), 64, 0, stream>>>(
        Q, Kb, Vb, seg_rows, seg_off, out);
}

// Round 8
// 112.308 us; speedup vs baseline: 1.1839x; 1.1839x over previous
//
#include <hip/hip_runtime.h>
#include <math.h>

#define N 4096
#define P 128
#define H 4
#define E 32
#define NSEG 32
#define TPB 256

// proj: 64-row tiles x 3 matrices = 192 tasks (+1 sort block = 193 blocks)
#define PROJ_TASKS 192

// attention: 4 waves/block, intra-block split-K, one query per lane
#define QW 3             // query-batch splits per (seg, head) -> grid z
#define KCH 48           // max keys staged per wave slice
#define LROW 36          // padded LDS row stride (floats)
#define WLDS (KCH * LROW * 2)   // floats per wave region (Ks+Vs) = 3456
#define G 8              // key group size (chain-breaking batch)
#define NEGF -3.0e38f

// ---------------------------------------------------------------------------
// Counting sort (single block, LDS atomics).
// ---------------------------------------------------------------------------
__device__ __forceinline__ void sort_phase(const int* __restrict__ pos,
                                           int* __restrict__ seg_rows,
                                           int* __restrict__ seg_off,
                                           int* sm, int t) {
    int* cnt = sm;              // NSEG
    int* cur = sm + NSEG;       // NSEG
    int* off = sm + 2 * NSEG;   // NSEG+1
    if (t < NSEG) cnt[t] = 0;
    __syncthreads();
    for (int i = t; i < N; i += TPB) atomicAdd(&cnt[pos[i]], 1);
    __syncthreads();
    if (t == 0) {
        int s = 0;
        for (int k = 0; k < NSEG; ++k) { off[k] = s; s += cnt[k]; }
        off[NSEG] = s;
    }
    __syncthreads();
    if (t <= NSEG) seg_off[t] = off[t];
    if (t < NSEG) cur[t] = off[t];
    __syncthreads();
    for (int i = t; i < N; i += TPB) {
        int r = atomicAdd(&cur[pos[i]], 1);
        seg_rows[r] = i;
    }
}

// ---------------------------------------------------------------------------
// One 64-row QKV projection tile. task in [0,192): mat=task>>6, tile=task&63.
// ---------------------------------------------------------------------------
__device__ __forceinline__ void proj_phase(int task,
                                           const float* __restrict__ x,
                                           const float* __restrict__ Wq, const float* __restrict__ bq,
                                           const float* __restrict__ Wk, const float* __restrict__ bk,
                                           const float* __restrict__ Wv, const float* __restrict__ bv,
                                           float* __restrict__ Q, float* __restrict__ Ko, float* __restrict__ Vo,
                                           float* sm, int t) {
    float* Xl = sm;           // [64][128]
    float* Wl = sm + 8192;    // [32][128]

    const int mat = task >> 6;
    const int r0  = (task & 63) * 64;
    const float* W = (mat == 0) ? Wq : (mat == 1) ? Wk : Wv;
    const float* b = (mat == 0) ? bq : (mat == 1) ? bk : bv;
    float* y       = (mat == 0) ? Q  : (mat == 1) ? Ko : Vo;

    for (int i = t * 4; i < 64 * 128; i += TPB * 4) {
        *(float4*)(Xl + i) = *(const float4*)(x + (size_t)r0 * 128 + i);
    }

    const int tc = t & 31;
    const int tr = t >> 5;

    float4 bb = *(const float4*)(b + tc * 4);
    float4 acc[8];
#pragma unroll
    for (int r = 0; r < 8; ++r) acc[r] = bb;

    for (int kc = 0; kc < 128; kc += 32) {
        __syncthreads();
        for (int i = t * 4; i < 32 * 128; i += TPB * 4) {
            *(float4*)(Wl + i) = *(const float4*)(W + (size_t)kc * 128 + i);
        }
        __syncthreads();
#pragma unroll
        for (int k0 = 0; k0 < 32; k0 += 4) {
            float4 w0 = *(float4*)&Wl[(k0 + 0) * 128 + tc * 4];
            float4 w1 = *(float4*)&Wl[(k0 + 1) * 128 + tc * 4];
            float4 w2 = *(float4*)&Wl[(k0 + 2) * 128 + tc * 4];
            float4 w3 = *(float4*)&Wl[(k0 + 3) * 128 + tc * 4];
#pragma unroll
            for (int r = 0; r < 8; ++r) {
                float4 xv = *(float4*)&Xl[(tr * 8 + r) * 128 + kc + k0];
                acc[r].x = fmaf(xv.x, w0.x, acc[r].x);
                acc[r].y = fmaf(xv.x, w0.y, acc[r].y);
                acc[r].z = fmaf(xv.x, w0.z, acc[r].z);
                acc[r].w = fmaf(xv.x, w0.w, acc[r].w);
                acc[r].x = fmaf(xv.y, w1.x, acc[r].x);
                acc[r].y = fmaf(xv.y, w1.y, acc[r].y);
                acc[r].z = fmaf(xv.y, w1.z, acc[r].z);
                acc[r].w = fmaf(xv.y, w1.w, acc[r].w);
                acc[r].x = fmaf(xv.z, w2.x, acc[r].x);
                acc[r].y = fmaf(xv.z, w2.y, acc[r].y);
                acc[r].z = fmaf(xv.z, w2.z, acc[r].z);
                acc[r].w = fmaf(xv.z, w2.w, acc[r].w);
                acc[r].x = fmaf(xv.w, w3.x, acc[r].x);
                acc[r].y = fmaf(xv.w, w3.y, acc[r].y);
                acc[r].z = fmaf(xv.w, w3.z, acc[r].z);
                acc[r].w = fmaf(xv.w, w3.w, acc[r].w);
            }
        }
    }

#pragma unroll
    for (int r = 0; r < 8; ++r) {
        *(float4*)(y + (size_t)(r0 + tr * 8 + r) * 128 + tc * 4) = acc[r];
    }
}

// ---------------------------------------------------------------------------
// Dispatch 1: block 0 sorts; blocks 1..192 each do one 64-row proj tile.
// ---------------------------------------------------------------------------
__global__ __launch_bounds__(TPB) void sort_proj_kernel(
        const float* __restrict__ inp, const int* __restrict__ pos,
        const float* __restrict__ Wq, const float* __restrict__ bq,
        const float* __restrict__ Wk, const float* __restrict__ bk,
        const float* __restrict__ Wv, const float* __restrict__ bv,
        float* __restrict__ Q, float* __restrict__ Kb, float* __restrict__ Vb,
        int* __restrict__ seg_rows, int* __restrict__ seg_off) {
    __shared__ __align__(16) float sm[12288];   // 48 KB
    const int b = blockIdx.x;
    const int t = threadIdx.x;
    if (b == 0) {
        sort_phase(pos, seg_rows, seg_off, (int*)sm, t);
    } else {
        proj_phase(b - 1, inp, Wq, bq, Wk, bk, Wv, bv, Q, Kb, Vb, sm, t);
    }
}

// ---------------------------------------------------------------------------
// Dispatch 2: attention. Block = 4 waves; wave w sweeps key slice
// [w*len/4,(w+1)*len/4) for the SAME 64 queries (one per lane, q/acc in
// registers, broadcast LDS reads). Each wave has a private LDS region; no
// barriers in the sweep. Partials merged in-block by wave 0.
// LDS region layout (floats, per wave): [0..KCH*LROW) Ks, then Vs.
// Partials overlay the wave's own Ks area after its sweep:
//   acc at e*64+lane (column-major, conflict-free), m at 2048+lane, l at 2112+lane.
// ---------------------------------------------------------------------------
__global__ __launch_bounds__(TPB) void attn_kernel(const float* __restrict__ Q,
                                                   const float* __restrict__ K,
                                                   const float* __restrict__ V,
                                                   const int* __restrict__ seg_rows,
                                                   const int* __restrict__ seg_off,
                                                   float* __restrict__ out) {
    __shared__ __align__(16) float sm[4 * WLDS];   // 55.3 KB

    const int s    = blockIdx.x;
    const int h    = blockIdx.y;
    const int z    = blockIdx.z;
    const int beg  = seg_off[s];
    const int len  = seg_off[s + 1] - beg;
    if (z * 64 >= len) return;                 // dead query batch: whole block exits
    const int t    = threadIdx.x;
    const int w    = t >> 6;
    const int lane = t & 63;
    const float scale = 0.17677669529663687f;  // 1/sqrt(32)

    float* Ks = sm + w * WLDS;
    float* Vs = Ks + KCH * LROW;

    const int k0 = (len * w) >> 2;
    const int k1 = (len * (w + 1)) >> 2;

    for (int qb = z * 64; qb < len; qb += QW * 64) {
        const int  qi     = qb + lane;
        const bool active = (qi < len);
        const int  qrow   = seg_rows[beg + (active ? qi : 0)];

        float q[E];
        {
            const float* qp = Q + (size_t)qrow * P + h * E;
#pragma unroll
            for (int e = 0; e < E; e += 4) {
                float4 v4 = *(const float4*)(qp + e);
                q[e] = v4.x; q[e + 1] = v4.y; q[e + 2] = v4.z; q[e + 3] = v4.w;
            }
        }

        float m = NEGF, l = 0.f;
        float acc[E];
#pragma unroll
        for (int e = 0; e < E; ++e) acc[e] = 0.f;

        for (int cb = k0; cb < k1; cb += KCH) {
            const int cl = min(KCH, k1 - cb);
            // stage this wave's K/V slice (wave-local; compiler waitcnts order LDS RAW)
            for (int idx = lane; idx < cl * E; idx += 64) {
                const int r = idx >> 5, e = idx & 31;
                const int krow = seg_rows[beg + cb + r];
                Ks[r * LROW + e] = K[(size_t)krow * P + h * E + e];
                Vs[r * LROW + e] = V[(size_t)krow * P + h * E + e];
            }

            for (int g = 0; g < cl; g += G) {
                float sc[G];
                int   ro[G];
#pragma unroll
                for (int i = 0; i < G; ++i) {
                    const int r = g + i;
                    ro[i] = (r < cl ? r : cl - 1) * LROW;
                    const float* kr = Ks + ro[i];
                    float d0 = 0.f, d1 = 0.f, d2 = 0.f, d3 = 0.f;
#pragma unroll
                    for (int e = 0; e < E; e += 4) {
                        float4 kv = *(const float4*)(kr + e);
                        d0 = fmaf(q[e],     kv.x, d0);
                        d1 = fmaf(q[e + 1], kv.y, d1);
                        d2 = fmaf(q[e + 2], kv.z, d2);
                        d3 = fmaf(q[e + 3], kv.w, d3);
                    }
                    const float d = (d0 + d1) + (d2 + d3);
                    sc[i] = (r < cl) ? d * scale : NEGF;
                }
                const float g0 = fmaxf(fmaxf(sc[0], sc[1]), fmaxf(sc[2], sc[3]));
                const float g1 = fmaxf(fmaxf(sc[4], sc[5]), fmaxf(sc[6], sc[7]));
                const float mn   = fmaxf(m, fmaxf(g0, g1));
                const float corr = __expf(m - mn);
                m = mn;
                float p[G];
#pragma unroll
                for (int i = 0; i < G; ++i) p[i] = __expf(sc[i] - mn);
                const float sp = ((p[0] + p[1]) + (p[2] + p[3]))
                               + ((p[4] + p[5]) + (p[6] + p[7]));
                l = fmaf(l, corr, sp);
#pragma unroll
                for (int e = 0; e < E; ++e) acc[e] *= corr;
#pragma unroll
                for (int i = 0; i < G; ++i) {
                    const float* vr = Vs + ro[i];
                    const float pi = p[i];
#pragma unroll
                    for (int e = 0; e < E; e += 4) {
                        float4 vv = *(const float4*)(vr + e);
                        acc[e]     = fmaf(pi, vv.x, acc[e]);
                        acc[e + 1] = fmaf(pi, vv.y, acc[e + 1]);
                        acc[e + 2] = fmaf(pi, vv.z, acc[e + 2]);
                        acc[e + 3] = fmaf(pi, vv.w, acc[e + 3]);
                    }
                }
            }
        }

        // publish partials into this wave's own region (sweep done, safe overlay)
#pragma unroll
        for (int e = 0; e < E; ++e) Ks[e * 64 + lane] = acc[e];   // column-major
        Ks[2048 + lane] = m;
        Ks[2112 + lane] = l;
        __syncthreads();

        // wave 0 merges the 4 partials per query and writes out
        if (w == 0) {
            float mm = NEGF;
            float2 ml[4];
#pragma unroll
            for (int wv = 0; wv < 4; ++wv) {
                const float* rg = sm + wv * WLDS;
                ml[wv] = make_float2(rg[2048 + lane], rg[2112 + lane]);
                mm = fmaxf(mm, ml[wv].x);
            }
            float wgt[4], ll = 0.f;
#pragma unroll
            for (int wv = 0; wv < 4; ++wv) {
                wgt[wv] = __expf(ml[wv].x - mm);
                ll = fmaf(ml[wv].y, wgt[wv], ll);
            }
            if (active) {
                const float inv = 1.0f / ll;
                float* op = out + (size_t)qrow * P + h * E;
#pragma unroll
                for (int e = 0; e < E; e += 4) {
                    float4 o = make_float4(0.f, 0.f, 0.f, 0.f);
#pragma unroll
                    for (int wv = 0; wv < 4; ++wv) {
                        const float* rg = sm + wv * WLDS;
                        const float g4 = wgt[wv];
                        o.x = fmaf(rg[(e + 0) * 64 + lane], g4, o.x);
                        o.y = fmaf(rg[(e + 1) * 64 + lane], g4, o.y);
                        o.z = fmaf(rg[(e + 2) * 64 + lane], g4, o.z);
                        o.w = fmaf(rg[(e + 3) * 64 + lane], g4, o.w);
                    }
                    o.x *= inv; o.y *= inv; o.z *= inv; o.w *= inv;
                    *(float4*)(op + e) = o;
                }
            }
        }
        __syncthreads();   // protect partial regions before next batch re-stages
    }
}

// ---------------------------------------------------------------------------
extern "C" void kernel_launch(void* const* d_in, const int* in_sizes, int n_in,
                              void* d_out, int out_size, void* d_ws, size_t ws_size,
                              hipStream_t stream) {
    const float* inp = (const float*)d_in[0];
    const int*   pos = (const int*)d_in[1];
    const float* Wq  = (const float*)d_in[2];
    const float* bq  = (const float*)d_in[3];
    const float* Wk  = (const float*)d_in[4];
    const float* bk  = (const float*)d_in[5];
    const float* Wv  = (const float*)d_in[6];
    const float* bv  = (const float*)d_in[7];
    float* out = (float*)d_out;

    float* Q  = (float*)d_ws;
    float* Kb = Q + (size_t)N * P;
    float* Vb = Kb + (size_t)N * P;
    int* seg_rows = (int*)(Vb + (size_t)N * P);
    int* seg_off  = seg_rows + N;          // NSEG+1

    sort_proj_kernel<<<1 + PROJ_TASKS, TPB, 0, stream>>>(
        inp, pos, Wq, bq, Wk, bk, Wv, bv, Q, Kb, Vb, seg_rows, seg_off);

    attn_kernel<<<dim3(NSEG, H, QW), TPB, 0, stream>>>(
        Q, Kb, Vb, seg_rows, seg_off, out);
}

// Round 9
// 109.360 us; speedup vs baseline: 1.2158x; 1.0270x over previous
//
#include <hip/hip_runtime.h>
#include <hip/hip_bf16.h>
#include <math.h>

#define N 4096
#define P 128
#define H 4
#define E 32
#define NSEG 32
#define TPB 256
#define PROJ_TASKS 192

#define LENMAX 256
#define VSTRIDE 264          // u16 units per Vt/Ps LDS row (16B-aligned, odd bank stride)
#define NEGF -3.0e38f

typedef __attribute__((ext_vector_type(8))) short bf16x8;
typedef __attribute__((ext_vector_type(4))) float f32x4;
typedef unsigned short u16;

__device__ __forceinline__ u16 f2b(float x) {
    __hip_bfloat16 b = __float2bfloat16(x);
    return *(u16*)&b;
}

// ---------------------------------------------------------------------------
// Counting sort (single block, LDS atomics).
// ---------------------------------------------------------------------------
__device__ __forceinline__ void sort_phase(const int* __restrict__ pos,
                                           int* __restrict__ seg_rows,
                                           int* __restrict__ seg_off,
                                           int* sm, int t) {
    int* cnt = sm;
    int* cur = sm + NSEG;
    int* off = sm + 2 * NSEG;
    if (t < NSEG) cnt[t] = 0;
    __syncthreads();
    for (int i = t; i < N; i += TPB) atomicAdd(&cnt[pos[i]], 1);
    __syncthreads();
    if (t == 0) {
        int s = 0;
        for (int k = 0; k < NSEG; ++k) { off[k] = s; s += cnt[k]; }
        off[NSEG] = s;
    }
    __syncthreads();
    if (t <= NSEG) seg_off[t] = off[t];
    if (t < NSEG) cur[t] = off[t];
    __syncthreads();
    for (int i = t; i < N; i += TPB) {
        int r = atomicAdd(&cur[pos[i]], 1);
        seg_rows[r] = i;
    }
}

// ---------------------------------------------------------------------------
// One 64-row QKV projection tile; fp32 accumulate, bf16 store.
// ---------------------------------------------------------------------------
__device__ __forceinline__ void proj_phase(int task,
                                           const float* __restrict__ x,
                                           const float* __restrict__ Wq, const float* __restrict__ bq,
                                           const float* __restrict__ Wk, const float* __restrict__ bk,
                                           const float* __restrict__ Wv, const float* __restrict__ bv,
                                           u16* __restrict__ Q, u16* __restrict__ Ko, u16* __restrict__ Vo,
                                           float* sm, int t) {
    float* Xl = sm;           // [64][128]
    float* Wl = sm + 8192;    // [32][128]

    const int mat = task >> 6;
    const int r0  = (task & 63) * 64;
    const float* W = (mat == 0) ? Wq : (mat == 1) ? Wk : Wv;
    const float* b = (mat == 0) ? bq : (mat == 1) ? bk : bv;
    u16* y         = (mat == 0) ? Q  : (mat == 1) ? Ko : Vo;

    for (int i = t * 4; i < 64 * 128; i += TPB * 4) {
        *(float4*)(Xl + i) = *(const float4*)(x + (size_t)r0 * 128 + i);
    }

    const int tc = t & 31;
    const int tr = t >> 5;

    float4 bb = *(const float4*)(b + tc * 4);
    float4 acc[8];
#pragma unroll
    for (int r = 0; r < 8; ++r) acc[r] = bb;

    for (int kc = 0; kc < 128; kc += 32) {
        __syncthreads();
        for (int i = t * 4; i < 32 * 128; i += TPB * 4) {
            *(float4*)(Wl + i) = *(const float4*)(W + (size_t)kc * 128 + i);
        }
        __syncthreads();
#pragma unroll
        for (int k0 = 0; k0 < 32; k0 += 4) {
            float4 w0 = *(float4*)&Wl[(k0 + 0) * 128 + tc * 4];
            float4 w1 = *(float4*)&Wl[(k0 + 1) * 128 + tc * 4];
            float4 w2 = *(float4*)&Wl[(k0 + 2) * 128 + tc * 4];
            float4 w3 = *(float4*)&Wl[(k0 + 3) * 128 + tc * 4];
#pragma unroll
            for (int r = 0; r < 8; ++r) {
                float4 xv = *(float4*)&Xl[(tr * 8 + r) * 128 + kc + k0];
                acc[r].x = fmaf(xv.x, w0.x, acc[r].x);
                acc[r].y = fmaf(xv.x, w0.y, acc[r].y);
                acc[r].z = fmaf(xv.x, w0.z, acc[r].z);
                acc[r].w = fmaf(xv.x, w0.w, acc[r].w);
                acc[r].x = fmaf(xv.y, w1.x, acc[r].x);
                acc[r].y = fmaf(xv.y, w1.y, acc[r].y);
                acc[r].z = fmaf(xv.y, w1.z, acc[r].z);
                acc[r].w = fmaf(xv.y, w1.w, acc[r].w);
                acc[r].x = fmaf(xv.z, w2.x, acc[r].x);
                acc[r].y = fmaf(xv.z, w2.y, acc[r].y);
                acc[r].z = fmaf(xv.z, w2.z, acc[r].z);
                acc[r].w = fmaf(xv.z, w2.w, acc[r].w);
                acc[r].x = fmaf(xv.w, w3.x, acc[r].x);
                acc[r].y = fmaf(xv.w, w3.y, acc[r].y);
                acc[r].z = fmaf(xv.w, w3.z, acc[r].z);
                acc[r].w = fmaf(xv.w, w3.w, acc[r].w);
            }
        }
    }

#pragma unroll
    for (int r = 0; r < 8; ++r) {
        ushort4 st;
        st.x = f2b(acc[r].x); st.y = f2b(acc[r].y);
        st.z = f2b(acc[r].z); st.w = f2b(acc[r].w);
        *(ushort4*)(y + (size_t)(r0 + tr * 8 + r) * 128 + tc * 4) = st;
    }
}

// ---------------------------------------------------------------------------
// Dispatch 1: block 0 sorts; blocks 1..192 do proj tiles.
// ---------------------------------------------------------------------------
__global__ __launch_bounds__(TPB) void sort_proj_kernel(
        const float* __restrict__ inp, const int* __restrict__ pos,
        const float* __restrict__ Wq, const float* __restrict__ bq,
        const float* __restrict__ Wk, const float* __restrict__ bk,
        const float* __restrict__ Wv, const float* __restrict__ bv,
        u16* __restrict__ Q, u16* __restrict__ Kb, u16* __restrict__ Vb,
        int* __restrict__ seg_rows, int* __restrict__ seg_off) {
    __shared__ __align__(16) float sm[12288];   // 48 KB
    const int b = blockIdx.x;
    const int t = threadIdx.x;
    if (b == 0) {
        sort_phase(pos, seg_rows, seg_off, (int*)sm, t);
    } else {
        proj_phase(b - 1, inp, Wq, bq, Wk, bk, Wv, bv, Q, Kb, Vb, sm, t);
    }
}

// ---------------------------------------------------------------------------
// Dispatch 2: MFMA attention. Grid (NSEG, H, 2), block 256 = 4 waves.
// Wave handles 16-query tiles tt = z*4+w, +8, ... Fragment layouts
// (mfma_f32_16x16x32_bf16, verified m89/m91/m120):
//   A[m=lane&15][k=quad*8+j]   B[k=quad*8+j][n=lane&15]
//   C/D: col=lane&15, row=quad*4+reg
// S = Q@K^T from global bf16 gathers; two-pass softmax with S strip in regs
// (row stats via 16-lane shfl_xor); P -> A-layout via per-wave LDS round
// trip; V staged once per block into LDS transposed (Vt[e][key]).
// ---------------------------------------------------------------------------
__global__ __launch_bounds__(TPB) void attn_kernel(const u16* __restrict__ Qb,
                                                   const u16* __restrict__ Kb,
                                                   const u16* __restrict__ Vb,
                                                   const int* __restrict__ seg_rows,
                                                   const int* __restrict__ seg_off,
                                                   float* __restrict__ out) {
    __shared__ u16 smu[VSTRIDE * (32 + 4 * 16)];   // Vt(32 rows) + 4 waves x Ps(16 rows) ~ 50.7 KB

    const int s = blockIdx.x, h = blockIdx.y, z = blockIdx.z;
    const int beg = seg_off[s];
    const int len = seg_off[s + 1] - beg;
    if (z * 64 >= len) return;
    const int t = threadIdx.x, w = t >> 6;
    const int lane = t & 63, col = lane & 15, quad = lane >> 4;
    const float scale = 0.17677669529663687f;   // 1/sqrt(32)

    int KT2 = ((len + 31) >> 5) << 5;           // keys padded to 32
    if (KT2 > LENMAX) KT2 = LENMAX;
    const int TS = KT2 >> 4;                    // 16-wide S tiles (<=16)
    const int KG = KT2 >> 5;                    // 32-wide PV key groups (<=8)

    // ---- stage V transposed: Vt[e][key], zero-padded to KT2 ----
    u16* Vt = smu;
    for (int idx = t; idx < 32 * KT2; idx += TPB) {
        const int e = idx & 31, key = idx >> 5;
        u16 v = 0;
        if (key < len) v = Vb[(size_t)seg_rows[beg + key] * 128 + h * 32 + e];
        Vt[e * VSTRIDE + key] = v;
    }
    __syncthreads();

    u16* Ps = smu + (32 + w * 16) * VSTRIDE;    // per-wave P buffer [16][VSTRIDE]

    for (int tt = z * 4 + w; tt * 16 < len; tt += 8) {
        // Q A-fragment (row m = col)
        const int qi = beg + min(tt * 16 + col, len - 1);
        const bf16x8 qa = *(const bf16x8*)(Qb + (size_t)seg_rows[qi] * 128 + h * 32 + quad * 8);

        f32x4 S[16];
        float mrow[4] = {NEGF, NEGF, NEGF, NEGF};
#pragma unroll
        for (int kt = 0; kt < 16; ++kt) {
            if (kt >= TS) break;
            const int ki = beg + min(kt * 16 + col, len - 1);
            const bf16x8 kb = *(const bf16x8*)(Kb + (size_t)seg_rows[ki] * 128 + h * 32 + quad * 8);
            f32x4 c = {0.f, 0.f, 0.f, 0.f};
            c = __builtin_amdgcn_mfma_f32_16x16x32_bf16(qa, kb, c, 0, 0, 0);
            const bool kvalid = (kt * 16 + col) < len;
#pragma unroll
            for (int r = 0; r < 4; ++r) {
                const float sc = kvalid ? c[r] * scale : NEGF;
                S[kt][r] = sc;
                mrow[r] = fmaxf(mrow[r], sc);
            }
        }
        // row max across the 16-lane col group
#pragma unroll
        for (int d = 1; d < 16; d <<= 1) {
#pragma unroll
            for (int r = 0; r < 4; ++r)
                mrow[r] = fmaxf(mrow[r], __shfl_xor(mrow[r], d));
        }
        float lrow[4] = {0.f, 0.f, 0.f, 0.f};
#pragma unroll
        for (int kt = 0; kt < 16; ++kt) {
            if (kt >= TS) break;
#pragma unroll
            for (int r = 0; r < 4; ++r) {
                const float p = __expf(S[kt][r] - mrow[r]);
                S[kt][r] = p;
                lrow[r] += p;
            }
        }
#pragma unroll
        for (int d = 1; d < 16; d <<= 1) {
#pragma unroll
            for (int r = 0; r < 4; ++r)
                lrow[r] += __shfl_xor(lrow[r], d);
        }
        // write P (unnormalized) to Ps[q][key] as bf16
#pragma unroll
        for (int kt = 0; kt < 16; ++kt) {
            if (kt >= TS) break;
#pragma unroll
            for (int r = 0; r < 4; ++r)
                Ps[(quad * 4 + r) * VSTRIDE + kt * 16 + col] = f2b(S[kt][r]);
        }
        // PV: A = P (m=col), B = Vt columns (n=col), accumulate 16x32 output
        f32x4 o0 = {0.f, 0.f, 0.f, 0.f}, o1 = {0.f, 0.f, 0.f, 0.f};
#pragma unroll
        for (int kg = 0; kg < 8; ++kg) {
            if (kg >= KG) break;
            const bf16x8 pa = *(const bf16x8*)(Ps + col * VSTRIDE + kg * 32 + quad * 8);
            const bf16x8 v0 = *(const bf16x8*)(Vt + col * VSTRIDE + kg * 32 + quad * 8);
            const bf16x8 v1 = *(const bf16x8*)(Vt + (16 + col) * VSTRIDE + kg * 32 + quad * 8);
            o0 = __builtin_amdgcn_mfma_f32_16x16x32_bf16(pa, v0, o0, 0, 0, 0);
            o1 = __builtin_amdgcn_mfma_f32_16x16x32_bf16(pa, v1, o1, 0, 0, 0);
        }
        // store: row q = quad*4+r, cols e = col and 16+col
#pragma unroll
        for (int r = 0; r < 4; ++r) {
            const int qloc = tt * 16 + quad * 4 + r;
            if (qloc < len) {
                const float inv = 1.0f / lrow[r];
                float* op = out + (size_t)seg_rows[beg + qloc] * 128 + h * 32;
                op[col]      = o0[r] * inv;
                op[16 + col] = o1[r] * inv;
            }
        }
    }
}

// ---------------------------------------------------------------------------
extern "C" void kernel_launch(void* const* d_in, const int* in_sizes, int n_in,
                              void* d_out, int out_size, void* d_ws, size_t ws_size,
                              hipStream_t stream) {
    const float* inp = (const float*)d_in[0];
    const int*   pos = (const int*)d_in[1];
    const float* Wq  = (const float*)d_in[2];
    const float* bq  = (const float*)d_in[3];
    const float* Wk  = (const float*)d_in[4];
    const float* bk  = (const float*)d_in[5];
    const float* Wv  = (const float*)d_in[6];
    const float* bv  = (const float*)d_in[7];
    float* out = (float*)d_out;

    // workspace: Q/K/V bf16 [N][128], then seg_rows, seg_off
    u16* Qb = (u16*)d_ws;
    u16* Kb = Qb + (size_t)N * 128;
    u16* Vb = Kb + (size_t)N * 128;
    int* seg_rows = (int*)(Vb + (size_t)N * 128);
    int* seg_off  = seg_rows + N;          // NSEG+1

    sort_proj_kernel<<<1 + PROJ_TASKS, TPB, 0, stream>>>(
        inp, pos, Wq, bq, Wk, bk, Wv, bv, Qb, Kb, Vb, seg_rows, seg_off);

    attn_kernel<<<dim3(NSEG, H, 2), TPB, 0, stream>>>(
        Qb, Kb, Vb, seg_rows, seg_off, out);
}

// Round 10
// 102.241 us; speedup vs baseline: 1.3004x; 1.0696x over previous
//
#include <hip/hip_runtime.h>
#include <hip/hip_bf16.h>
#include <math.h>

#define N 4096
#define P 128
#define H 4
#define E 32
#define NSEG 32
#define TPB 256
#define PROJ_TASKS 192

#define LENMAX 256
#define VSTRIDE 264          // u16 units per Vt/Ps LDS row
#define NEGF -3.0e38f

typedef __attribute__((ext_vector_type(8))) short bf16x8;
typedef __attribute__((ext_vector_type(4))) float f32x4;
typedef unsigned short u16;

__device__ __forceinline__ u16 f2b(float x) {
    __hip_bfloat16 b = __float2bfloat16(x);
    return *(u16*)&b;
}

// ---------------------------------------------------------------------------
// Counting sort (single block, LDS atomics).
// ---------------------------------------------------------------------------
__device__ __forceinline__ void sort_phase(const int* __restrict__ pos,
                                           int* __restrict__ seg_rows,
                                           int* __restrict__ seg_off,
                                           int* sm, int t) {
    int* cnt = sm;
    int* cur = sm + NSEG;
    int* off = sm + 2 * NSEG;
    if (t < NSEG) cnt[t] = 0;
    __syncthreads();
    for (int i = t; i < N; i += TPB) atomicAdd(&cnt[pos[i]], 1);
    __syncthreads();
    if (t == 0) {
        int s = 0;
        for (int k = 0; k < NSEG; ++k) { off[k] = s; s += cnt[k]; }
        off[NSEG] = s;
    }
    __syncthreads();
    if (t <= NSEG) seg_off[t] = off[t];
    if (t < NSEG) cur[t] = off[t];
    __syncthreads();
    for (int i = t; i < N; i += TPB) {
        int r = atomicAdd(&cur[pos[i]], 1);
        seg_rows[r] = i;
    }
}

// ---------------------------------------------------------------------------
// One 64-row QKV projection tile; fp32 accumulate, bf16 store.
// ---------------------------------------------------------------------------
__device__ __forceinline__ void proj_phase(int task,
                                           const float* __restrict__ x,
                                           const float* __restrict__ Wq, const float* __restrict__ bq,
                                           const float* __restrict__ Wk, const float* __restrict__ bk,
                                           const float* __restrict__ Wv, const float* __restrict__ bv,
                                           u16* __restrict__ Q, u16* __restrict__ Ko, u16* __restrict__ Vo,
                                           float* sm, int t) {
    float* Xl = sm;           // [64][128]
    float* Wl = sm + 8192;    // [32][128]

    const int mat = task >> 6;
    const int r0  = (task & 63) * 64;
    const float* W = (mat == 0) ? Wq : (mat == 1) ? Wk : Wv;
    const float* b = (mat == 0) ? bq : (mat == 1) ? bk : bv;
    u16* y         = (mat == 0) ? Q  : (mat == 1) ? Ko : Vo;

    for (int i = t * 4; i < 64 * 128; i += TPB * 4) {
        *(float4*)(Xl + i) = *(const float4*)(x + (size_t)r0 * 128 + i);
    }

    const int tc = t & 31;
    const int tr = t >> 5;

    float4 bb = *(const float4*)(b + tc * 4);
    float4 acc[8];
#pragma unroll
    for (int r = 0; r < 8; ++r) acc[r] = bb;

    for (int kc = 0; kc < 128; kc += 32) {
        __syncthreads();
        for (int i = t * 4; i < 32 * 128; i += TPB * 4) {
            *(float4*)(Wl + i) = *(const float4*)(W + (size_t)kc * 128 + i);
        }
        __syncthreads();
#pragma unroll
        for (int k0 = 0; k0 < 32; k0 += 4) {
            float4 w0 = *(float4*)&Wl[(k0 + 0) * 128 + tc * 4];
            float4 w1 = *(float4*)&Wl[(k0 + 1) * 128 + tc * 4];
            float4 w2 = *(float4*)&Wl[(k0 + 2) * 128 + tc * 4];
            float4 w3 = *(float4*)&Wl[(k0 + 3) * 128 + tc * 4];
#pragma unroll
            for (int r = 0; r < 8; ++r) {
                float4 xv = *(float4*)&Xl[(tr * 8 + r) * 128 + kc + k0];
                acc[r].x = fmaf(xv.x, w0.x, acc[r].x);
                acc[r].y = fmaf(xv.x, w0.y, acc[r].y);
                acc[r].z = fmaf(xv.x, w0.z, acc[r].z);
                acc[r].w = fmaf(xv.x, w0.w, acc[r].w);
                acc[r].x = fmaf(xv.y, w1.x, acc[r].x);
                acc[r].y = fmaf(xv.y, w1.y, acc[r].y);
                acc[r].z = fmaf(xv.y, w1.z, acc[r].z);
                acc[r].w = fmaf(xv.y, w1.w, acc[r].w);
                acc[r].x = fmaf(xv.z, w2.x, acc[r].x);
                acc[r].y = fmaf(xv.z, w2.y, acc[r].y);
                acc[r].z = fmaf(xv.z, w2.z, acc[r].z);
                acc[r].w = fmaf(xv.z, w2.w, acc[r].w);
                acc[r].x = fmaf(xv.w, w3.x, acc[r].x);
                acc[r].y = fmaf(xv.w, w3.y, acc[r].y);
                acc[r].z = fmaf(xv.w, w3.z, acc[r].z);
                acc[r].w = fmaf(xv.w, w3.w, acc[r].w);
            }
        }
    }

#pragma unroll
    for (int r = 0; r < 8; ++r) {
        ushort4 st;
        st.x = f2b(acc[r].x); st.y = f2b(acc[r].y);
        st.z = f2b(acc[r].z); st.w = f2b(acc[r].w);
        *(ushort4*)(y + (size_t)(r0 + tr * 8 + r) * 128 + tc * 4) = st;
    }
}

// ---------------------------------------------------------------------------
// Dispatch 1: block 0 sorts; blocks 1..192 do proj tiles.
// ---------------------------------------------------------------------------
__global__ __launch_bounds__(TPB) void sort_proj_kernel(
        const float* __restrict__ inp, const int* __restrict__ pos,
        const float* __restrict__ Wq, const float* __restrict__ bq,
        const float* __restrict__ Wk, const float* __restrict__ bk,
        const float* __restrict__ Wv, const float* __restrict__ bv,
        u16* __restrict__ Q, u16* __restrict__ Kb, u16* __restrict__ Vb,
        int* __restrict__ seg_rows, int* __restrict__ seg_off) {
    __shared__ __align__(16) float sm[12288];   // 48 KB
    const int b = blockIdx.x;
    const int t = threadIdx.x;
    if (b == 0) {
        sort_phase(pos, seg_rows, seg_off, (int*)sm, t);
    } else {
        proj_phase(b - 1, inp, Wq, bq, Wk, bk, Wv, bv, Q, Kb, Vb, sm, t);
    }
}

// ---------------------------------------------------------------------------
// MFMA attention tile helpers (mfma_f32_16x16x32_bf16 layouts, m89/m91/m120):
//   A[m=lane&15][k=quad*8+j]   B[k=quad*8+j][n=lane&15]
//   C/D: col=lane&15, row=quad*4+reg
// ---------------------------------------------------------------------------
__device__ __forceinline__ void tile_qk(int tt, int beg, int len, int h, int TS,
                                        const u16* __restrict__ Qb,
                                        const u16* __restrict__ Kb,
                                        const int* __restrict__ seg_rows,
                                        u16* __restrict__ Ps,
                                        int col, int quad, float* lrow) {
    const float scale = 0.17677669529663687f;   // 1/sqrt(32)
    const int qi = beg + min(tt * 16 + col, len - 1);
    const bf16x8 qa = *(const bf16x8*)(Qb + (size_t)seg_rows[qi] * 128 + h * 32 + quad * 8);

    f32x4 S[16];
    float mrow[4] = {NEGF, NEGF, NEGF, NEGF};
#pragma unroll
    for (int kt = 0; kt < 16; ++kt) {
        if (kt >= TS) break;
        const int ki = beg + min(kt * 16 + col, len - 1);
        const bf16x8 kb = *(const bf16x8*)(Kb + (size_t)seg_rows[ki] * 128 + h * 32 + quad * 8);
        f32x4 c = {0.f, 0.f, 0.f, 0.f};
        c = __builtin_amdgcn_mfma_f32_16x16x32_bf16(qa, kb, c, 0, 0, 0);
        const bool kvalid = (kt * 16 + col) < len;
#pragma unroll
        for (int r = 0; r < 4; ++r) {
            const float sc = kvalid ? c[r] * scale : NEGF;
            S[kt][r] = sc;
            mrow[r] = fmaxf(mrow[r], sc);
        }
    }
#pragma unroll
    for (int d = 1; d < 16; d <<= 1) {
#pragma unroll
        for (int r = 0; r < 4; ++r)
            mrow[r] = fmaxf(mrow[r], __shfl_xor(mrow[r], d));
    }
    lrow[0] = lrow[1] = lrow[2] = lrow[3] = 0.f;
#pragma unroll
    for (int kt = 0; kt < 16; ++kt) {
        if (kt >= TS) break;
#pragma unroll
        for (int r = 0; r < 4; ++r) {
            const float p = __expf(S[kt][r] - mrow[r]);
            S[kt][r] = p;
            lrow[r] += p;
        }
    }
#pragma unroll
    for (int d = 1; d < 16; d <<= 1) {
#pragma unroll
        for (int r = 0; r < 4; ++r)
            lrow[r] += __shfl_xor(lrow[r], d);
    }
#pragma unroll
    for (int kt = 0; kt < 16; ++kt) {
        if (kt >= TS) break;
#pragma unroll
        for (int r = 0; r < 4; ++r)
            Ps[(quad * 4 + r) * VSTRIDE + kt * 16 + col] = f2b(S[kt][r]);
    }
}

__device__ __forceinline__ void tile_pv(int tt, int beg, int len, int h, int KG,
                                        const u16* __restrict__ Vt,
                                        const u16* __restrict__ Ps,
                                        const int* __restrict__ seg_rows,
                                        float* __restrict__ out,
                                        int col, int quad, const float* lrow) {
    f32x4 o0 = {0.f, 0.f, 0.f, 0.f}, o1 = {0.f, 0.f, 0.f, 0.f};
#pragma unroll
    for (int kg = 0; kg < 8; ++kg) {
        if (kg >= KG) break;
        const bf16x8 pa = *(const bf16x8*)(Ps + col * VSTRIDE + kg * 32 + quad * 8);
        const bf16x8 v0 = *(const bf16x8*)(Vt + col * VSTRIDE + kg * 32 + quad * 8);
        const bf16x8 v1 = *(const bf16x8*)(Vt + (16 + col) * VSTRIDE + kg * 32 + quad * 8);
        o0 = __builtin_amdgcn_mfma_f32_16x16x32_bf16(pa, v0, o0, 0, 0, 0);
        o1 = __builtin_amdgcn_mfma_f32_16x16x32_bf16(pa, v1, o1, 0, 0, 0);
    }
#pragma unroll
    for (int r = 0; r < 4; ++r) {
        const int qloc = tt * 16 + quad * 4 + r;
        if (qloc < len) {
            const float inv = 1.0f / lrow[r];
            float* op = out + (size_t)seg_rows[beg + qloc] * 128 + h * 32;
            op[col]      = o0[r] * inv;
            op[16 + col] = o1[r] * inv;
        }
    }
}

// ---------------------------------------------------------------------------
// Dispatch 2: MFMA attention. Grid (NSEG, H, 2), block 256 = 4 waves.
// Vt staged with VECTOR loads (bf16x8) + transpose LDS writes; the single
// block barrier is placed AFTER the first tile's QK+softmax so the staging
// latency hides under compute. Later tiles need no barriers (per-wave Ps,
// read-only Vt).
// ---------------------------------------------------------------------------
__global__ __launch_bounds__(TPB) void attn_kernel(const u16* __restrict__ Qb,
                                                   const u16* __restrict__ Kb,
                                                   const u16* __restrict__ Vb,
                                                   const int* __restrict__ seg_rows,
                                                   const int* __restrict__ seg_off,
                                                   float* __restrict__ out) {
    __shared__ u16 smu[VSTRIDE * (32 + 4 * 16)];   // Vt(32) + 4x Ps(16) rows

    const int s = blockIdx.x, h = blockIdx.y, z = blockIdx.z;
    const int beg = seg_off[s];
    const int len = seg_off[s + 1] - beg;
    if (z * 64 >= len) return;
    const int t = threadIdx.x, w = t >> 6;
    const int lane = t & 63, col = lane & 15, quad = lane >> 4;

    int KT2 = ((len + 31) >> 5) << 5;
    if (KT2 > LENMAX) KT2 = LENMAX;
    const int TS = KT2 >> 4;
    const int KG = KT2 >> 5;

    // ---- stage V transposed with vector loads: Vt[e][key] ----
    u16* Vt = smu;
    for (int idx = t; idx < KT2 * 4; idx += TPB) {
        const int key = idx >> 2, c = idx & 3;
        bf16x8 v = {0, 0, 0, 0, 0, 0, 0, 0};
        if (key < len)
            v = *(const bf16x8*)(Vb + (size_t)seg_rows[beg + key] * 128 + h * 32 + c * 8);
#pragma unroll
        for (int j = 0; j < 8; ++j)
            Vt[(c * 8 + j) * VSTRIDE + key] = (u16)v[j];
    }
    // NO barrier yet — QK/softmax below doesn't touch Vt.

    u16* Ps = smu + (32 + w * 16) * VSTRIDE;

    const int tt0 = z * 4 + w;
    const bool have0 = (tt0 * 16 < len);
    float lr0[4];
    if (have0)
        tile_qk(tt0, beg, len, h, TS, Qb, Kb, seg_rows, Ps, col, quad, lr0);

    __syncthreads();   // Vt ready; executed exactly once by every thread

    if (have0)
        tile_pv(tt0, beg, len, h, KG, Vt, Ps, seg_rows, out, col, quad, lr0);

    for (int tt = tt0 + 8; tt * 16 < len; tt += 8) {
        float lr[4];
        tile_qk(tt, beg, len, h, TS, Qb, Kb, seg_rows, Ps, col, quad, lr);
        tile_pv(tt, beg, len, h, KG, Vt, Ps, seg_rows, out, col, quad, lr);
    }
}

// ---------------------------------------------------------------------------
extern "C" void kernel_launch(void* const* d_in, const int* in_sizes, int n_in,
                              void* d_out, int out_size, void* d_ws, size_t ws_size,
                              hipStream_t stream) {
    const float* inp = (const float*)d_in[0];
    const int*   pos = (const int*)d_in[1];
    const float* Wq  = (const float*)d_in[2];
    const float* bq  = (const float*)d_in[3];
    const float* Wk  = (const float*)d_in[4];
    const float* bk  = (const float*)d_in[5];
    const float* Wv  = (const float*)d_in[6];
    const float* bv  = (const float*)d_in[7];
    float* out = (float*)d_out;

    u16* Qb = (u16*)d_ws;
    u16* Kb = Qb + (size_t)N * 128;
    u16* Vb = Kb + (size_t)N * 128;
    int* seg_rows = (int*)(Vb + (size_t)N * 128);
    int* seg_off  = seg_rows + N;          // NSEG+1

    sort_proj_kernel<<<1 + PROJ_TASKS, TPB, 0, stream>>>(
        inp, pos, Wq, bq, Wk, bk, Wv, bv, Qb, Kb, Vb, seg_rows, seg_off);

    attn_kernel<<<dim3(NSEG, H, 2), TPB, 0, stream>>>(
        Qb, Kb, Vb, seg_rows, seg_off, out);
}

// Round 11
// 92.489 us; speedup vs baseline: 1.4376x; 1.1054x over previous
//
#include <hip/hip_runtime.h>
#include <hip/hip_bf16.h>
#include <math.h>

#define N 4096
#define P 128
#define H 4
#define E 32
#define NSEG 32
#define TPB 256
#define PROJ_TASKS 192

#define LENMAX 256
#define VSTRIDE 264          // u16 units per Vt/Ps LDS row
#define NEGF -3.0e38f

typedef __attribute__((ext_vector_type(8))) short bf16x8;
typedef __attribute__((ext_vector_type(4))) float f32x4;
typedef unsigned short u16;

__device__ __forceinline__ u16 f2b(float x) {
    __hip_bfloat16 b = __float2bfloat16(x);
    return *(u16*)&b;
}

// ---------------------------------------------------------------------------
// Counting sort (single block, LDS atomics).
// ---------------------------------------------------------------------------
__device__ __forceinline__ void sort_phase(const int* __restrict__ pos,
                                           int* __restrict__ seg_rows,
                                           int* __restrict__ seg_off,
                                           int* sm, int t) {
    int* cnt = sm;
    int* cur = sm + NSEG;
    int* off = sm + 2 * NSEG;
    if (t < NSEG) cnt[t] = 0;
    __syncthreads();
    for (int i = t; i < N; i += TPB) atomicAdd(&cnt[pos[i]], 1);
    __syncthreads();
    if (t == 0) {
        int s = 0;
        for (int k = 0; k < NSEG; ++k) { off[k] = s; s += cnt[k]; }
        off[NSEG] = s;
    }
    __syncthreads();
    if (t <= NSEG) seg_off[t] = off[t];
    if (t < NSEG) cur[t] = off[t];
    __syncthreads();
    for (int i = t; i < N; i += TPB) {
        int r = atomicAdd(&cur[pos[i]], 1);
        seg_rows[r] = i;
    }
}

// ---------------------------------------------------------------------------
// One 64-row QKV projection tile; fp32 accumulate, bf16 store.
// ---------------------------------------------------------------------------
__device__ __forceinline__ void proj_phase(int task,
                                           const float* __restrict__ x,
                                           const float* __restrict__ Wq, const float* __restrict__ bq,
                                           const float* __restrict__ Wk, const float* __restrict__ bk,
                                           const float* __restrict__ Wv, const float* __restrict__ bv,
                                           u16* __restrict__ Q, u16* __restrict__ Ko, u16* __restrict__ Vo,
                                           float* sm, int t) {
    float* Xl = sm;           // [64][128]
    float* Wl = sm + 8192;    // [32][128]

    const int mat = task >> 6;
    const int r0  = (task & 63) * 64;
    const float* W = (mat == 0) ? Wq : (mat == 1) ? Wk : Wv;
    const float* b = (mat == 0) ? bq : (mat == 1) ? bk : bv;
    u16* y         = (mat == 0) ? Q  : (mat == 1) ? Ko : Vo;

    for (int i = t * 4; i < 64 * 128; i += TPB * 4) {
        *(float4*)(Xl + i) = *(const float4*)(x + (size_t)r0 * 128 + i);
    }

    const int tc = t & 31;
    const int tr = t >> 5;

    float4 bb = *(const float4*)(b + tc * 4);
    float4 acc[8];
#pragma unroll
    for (int r = 0; r < 8; ++r) acc[r] = bb;

    for (int kc = 0; kc < 128; kc += 32) {
        __syncthreads();
        for (int i = t * 4; i < 32 * 128; i += TPB * 4) {
            *(float4*)(Wl + i) = *(const float4*)(W + (size_t)kc * 128 + i);
        }
        __syncthreads();
#pragma unroll
        for (int k0 = 0; k0 < 32; k0 += 4) {
            float4 w0 = *(float4*)&Wl[(k0 + 0) * 128 + tc * 4];
            float4 w1 = *(float4*)&Wl[(k0 + 1) * 128 + tc * 4];
            float4 w2 = *(float4*)&Wl[(k0 + 2) * 128 + tc * 4];
            float4 w3 = *(float4*)&Wl[(k0 + 3) * 128 + tc * 4];
#pragma unroll
            for (int r = 0; r < 8; ++r) {
                float4 xv = *(float4*)&Xl[(tr * 8 + r) * 128 + kc + k0];
                acc[r].x = fmaf(xv.x, w0.x, acc[r].x);
                acc[r].y = fmaf(xv.x, w0.y, acc[r].y);
                acc[r].z = fmaf(xv.x, w0.z, acc[r].z);
                acc[r].w = fmaf(xv.x, w0.w, acc[r].w);
                acc[r].x = fmaf(xv.y, w1.x, acc[r].x);
                acc[r].y = fmaf(xv.y, w1.y, acc[r].y);
                acc[r].z = fmaf(xv.y, w1.z, acc[r].z);
                acc[r].w = fmaf(xv.y, w1.w, acc[r].w);
                acc[r].x = fmaf(xv.z, w2.x, acc[r].x);
                acc[r].y = fmaf(xv.z, w2.y, acc[r].y);
                acc[r].z = fmaf(xv.z, w2.z, acc[r].z);
                acc[r].w = fmaf(xv.z, w2.w, acc[r].w);
                acc[r].x = fmaf(xv.w, w3.x, acc[r].x);
                acc[r].y = fmaf(xv.w, w3.y, acc[r].y);
                acc[r].z = fmaf(xv.w, w3.z, acc[r].z);
                acc[r].w = fmaf(xv.w, w3.w, acc[r].w);
            }
        }
    }

#pragma unroll
    for (int r = 0; r < 8; ++r) {
        ushort4 st;
        st.x = f2b(acc[r].x); st.y = f2b(acc[r].y);
        st.z = f2b(acc[r].z); st.w = f2b(acc[r].w);
        *(ushort4*)(y + (size_t)(r0 + tr * 8 + r) * 128 + tc * 4) = st;
    }
}

// ---------------------------------------------------------------------------
// Dispatch 1: block 0 sorts; blocks 1..192 do proj tiles.
// ---------------------------------------------------------------------------
__global__ __launch_bounds__(TPB) void sort_proj_kernel(
        const float* __restrict__ inp, const int* __restrict__ pos,
        const float* __restrict__ Wq, const float* __restrict__ bq,
        const float* __restrict__ Wk, const float* __restrict__ bk,
        const float* __restrict__ Wv, const float* __restrict__ bv,
        u16* __restrict__ Q, u16* __restrict__ Kb, u16* __restrict__ Vb,
        int* __restrict__ seg_rows, int* __restrict__ seg_off) {
    __shared__ __align__(16) float sm[12288];   // 48 KB
    const int b = blockIdx.x;
    const int t = threadIdx.x;
    if (b == 0) {
        sort_phase(pos, seg_rows, seg_off, (int*)sm, t);
    } else {
        proj_phase(b - 1, inp, Wq, bq, Wk, bk, Wv, bv, Q, Kb, Vb, sm, t);
    }
}

// ---------------------------------------------------------------------------
// MFMA attention tile helpers. ALL loops have compile-time trip counts —
// no runtime breaks (a runtime `break` in an unrolled loop makes each
// gather control-dependent on the previous branch, serializing 16 global
// loads at ~1.1k cyc each with 1 wave/SIMD to hide nothing).
// Invalid key columns are masked (p=0), clamped gathers are L1-hit dups.
// Layouts (mfma_f32_16x16x32_bf16, m89/m91/m120):
//   A[m=lane&15][k=quad*8+j]  B[k=quad*8+j][n=lane&15]
//   C/D: col=lane&15, row=quad*4+reg
// ---------------------------------------------------------------------------
__device__ __forceinline__ void tile_qk(int tt, int beg, int len, int h,
                                        const u16* __restrict__ Qb,
                                        const u16* __restrict__ Kb,
                                        const int* __restrict__ seg_rows,
                                        u16* __restrict__ Ps,
                                        int col, int quad, float* lrow) {
    const float scale = 0.17677669529663687f;   // 1/sqrt(32)
    const int qi = beg + min(tt * 16 + col, len - 1);
    const bf16x8 qa = *(const bf16x8*)(Qb + (size_t)seg_rows[qi] * 128 + h * 32 + quad * 8);

    // 16 independent row-id loads (single waitcnt batch)
    int krow[16];
#pragma unroll
    for (int kt = 0; kt < 16; ++kt)
        krow[kt] = seg_rows[beg + min(kt * 16 + col, len - 1)];

    // 16 independent K gathers + MFMAs (no control deps -> batched issue)
    f32x4 S[16];
#pragma unroll
    for (int kt = 0; kt < 16; ++kt) {
        const bf16x8 kb = *(const bf16x8*)(Kb + (size_t)krow[kt] * 128 + h * 32 + quad * 8);
        f32x4 c = {0.f, 0.f, 0.f, 0.f};
        S[kt] = __builtin_amdgcn_mfma_f32_16x16x32_bf16(qa, kb, c, 0, 0, 0);
    }

    float mrow[4] = {NEGF, NEGF, NEGF, NEGF};
#pragma unroll
    for (int kt = 0; kt < 16; ++kt) {
        const bool kvalid = (kt * 16 + col) < len;
#pragma unroll
        for (int r = 0; r < 4; ++r) {
            const float sc = kvalid ? S[kt][r] * scale : NEGF;
            S[kt][r] = sc;
            mrow[r] = fmaxf(mrow[r], sc);
        }
    }
#pragma unroll
    for (int d = 1; d < 16; d <<= 1) {
#pragma unroll
        for (int r = 0; r < 4; ++r)
            mrow[r] = fmaxf(mrow[r], __shfl_xor(mrow[r], d));
    }
    lrow[0] = lrow[1] = lrow[2] = lrow[3] = 0.f;
#pragma unroll
    for (int kt = 0; kt < 16; ++kt) {
#pragma unroll
        for (int r = 0; r < 4; ++r) {
            const float p = __expf(S[kt][r] - mrow[r]);   // masked cols -> exp(NEGF-m)=0
            S[kt][r] = p;
            lrow[r] += p;
        }
    }
#pragma unroll
    for (int d = 1; d < 16; d <<= 1) {
#pragma unroll
        for (int r = 0; r < 4; ++r)
            lrow[r] += __shfl_xor(lrow[r], d);
    }
    // full 256-wide Ps write (zeros beyond len)
#pragma unroll
    for (int kt = 0; kt < 16; ++kt) {
#pragma unroll
        for (int r = 0; r < 4; ++r)
            Ps[(quad * 4 + r) * VSTRIDE + kt * 16 + col] = f2b(S[kt][r]);
    }
}

__device__ __forceinline__ void tile_pv(int tt, int beg, int len, int h,
                                        const u16* __restrict__ Vt,
                                        const u16* __restrict__ Ps,
                                        const int* __restrict__ seg_rows,
                                        float* __restrict__ out,
                                        int col, int quad, const float* lrow) {
    f32x4 o0 = {0.f, 0.f, 0.f, 0.f}, o1 = {0.f, 0.f, 0.f, 0.f};
#pragma unroll
    for (int kg = 0; kg < 8; ++kg) {
        const bf16x8 pa = *(const bf16x8*)(Ps + col * VSTRIDE + kg * 32 + quad * 8);
        const bf16x8 v0 = *(const bf16x8*)(Vt + col * VSTRIDE + kg * 32 + quad * 8);
        const bf16x8 v1 = *(const bf16x8*)(Vt + (16 + col) * VSTRIDE + kg * 32 + quad * 8);
        o0 = __builtin_amdgcn_mfma_f32_16x16x32_bf16(pa, v0, o0, 0, 0, 0);
        o1 = __builtin_amdgcn_mfma_f32_16x16x32_bf16(pa, v1, o1, 0, 0, 0);
    }
#pragma unroll
    for (int r = 0; r < 4; ++r) {
        const int qloc = tt * 16 + quad * 4 + r;
        if (qloc < len) {
            const float inv = 1.0f / lrow[r];
            float* op = out + (size_t)seg_rows[beg + qloc] * 128 + h * 32;
            op[col]      = o0[r] * inv;
            op[16 + col] = o1[r] * inv;
        }
    }
}

// ---------------------------------------------------------------------------
// Dispatch 2: MFMA attention. Grid (NSEG, H, 2), block 256 = 4 waves.
// Vt staged full 256-wide (zero-padded) with vector loads; single barrier
// placed after the first tile's QK+softmax to hide staging latency.
// ---------------------------------------------------------------------------
__global__ __launch_bounds__(TPB) void attn_kernel(const u16* __restrict__ Qb,
                                                   const u16* __restrict__ Kb,
                                                   const u16* __restrict__ Vb,
                                                   const int* __restrict__ seg_rows,
                                                   const int* __restrict__ seg_off,
                                                   float* __restrict__ out) {
    __shared__ u16 smu[VSTRIDE * (32 + 4 * 16)];   // Vt(32 rows) + 4x Ps(16 rows)

    const int s = blockIdx.x, h = blockIdx.y, z = blockIdx.z;
    const int beg = seg_off[s];
    const int len = seg_off[s + 1] - beg;
    if (z * 64 >= len) return;
    const int t = threadIdx.x, w = t >> 6;
    const int lane = t & 63, col = lane & 15, quad = lane >> 4;

    // ---- stage V transposed, full LENMAX width, zero-padded ----
    u16* Vt = smu;
#pragma unroll
    for (int ii = 0; ii < 4; ++ii) {                 // 1024 = 4 * TPB slots
        const int idx = ii * TPB + t;
        const int key = idx >> 2, c = idx & 3;
        bf16x8 v = {0, 0, 0, 0, 0, 0, 0, 0};
        if (key < len)
            v = *(const bf16x8*)(Vb + (size_t)seg_rows[beg + key] * 128 + h * 32 + c * 8);
#pragma unroll
        for (int j = 0; j < 8; ++j)
            Vt[(c * 8 + j) * VSTRIDE + key] = (u16)v[j];
    }
    // no barrier yet — QK/softmax below doesn't touch Vt

    u16* Ps = smu + (32 + w * 16) * VSTRIDE;

    const int tt0 = z * 4 + w;
    const bool have0 = (tt0 * 16 < len);
    float lr0[4];
    if (have0)
        tile_qk(tt0, beg, len, h, Qb, Kb, seg_rows, Ps, col, quad, lr0);

    __syncthreads();   // Vt ready; executed exactly once by every thread

    if (have0)
        tile_pv(tt0, beg, len, h, Vt, Ps, seg_rows, out, col, quad, lr0);

    for (int tt = tt0 + 8; tt * 16 < len; tt += 8) {
        float lr[4];
        tile_qk(tt, beg, len, h, Qb, Kb, seg_rows, Ps, col, quad, lr);
        tile_pv(tt, beg, len, h, Vt, Ps, seg_rows, out, col, quad, lr);
    }
}

// ---------------------------------------------------------------------------
extern "C" void kernel_launch(void* const* d_in, const int* in_sizes, int n_in,
                              void* d_out, int out_size, void* d_ws, size_t ws_size,
                              hipStream_t stream) {
    const float* inp = (const float*)d_in[0];
    const int*   pos = (const int*)d_in[1];
    const float* Wq  = (const float*)d_in[2];
    const float* bq  = (const float*)d_in[3];
    const float* Wk  = (const float*)d_in[4];
    const float* bk  = (const float*)d_in[5];
    const float* Wv  = (const float*)d_in[6];
    const float* bv  = (const float*)d_in[7];
    float* out = (float*)d_out;

    u16* Qb = (u16*)d_ws;
    u16* Kb = Qb + (size_t)N * 128;
    u16* Vb = Kb + (size_t)N * 128;
    int* seg_rows = (int*)(Vb + (size_t)N * 128);
    int* seg_off  = seg_rows + N;          // NSEG+1

    sort_proj_kernel<<<1 + PROJ_TASKS, TPB, 0, stream>>>(
        inp, pos, Wq, bq, Wk, bk, Wv, bv, Qb, Kb, Vb, seg_rows, seg_off);

    attn_kernel<<<dim3(NSEG, H, 2), TPB, 0, stream>>>(
        Qb, Kb, Vb, seg_rows, seg_off, out);
}